// Round 1
// baseline (680.699 us; speedup 1.0000x reference)
//
#include <hip/hip_runtime.h>
#include <hip/hip_bf16.h>
#include <math.h>

// Problem constants (from reference)
#define B       32
#define S_CURR  128
#define D       512
#define H       8
#define DH      64
#define NM      16
#define GRID_N  40000
#define NCAND   39998          // emb[2:]
#define MG      (B * NM)       // 512 gathered rows
#define SCORE_LD 40064         // 313*128, padded row stride for scores in ws

typedef __bf16 bf16x8_t __attribute__((ext_vector_type(8)));
typedef __bf16 bf16x4_t __attribute__((ext_vector_type(4)));
typedef float  f32x4_t  __attribute__((ext_vector_type(4)));

// ---------------------------------------------------------------------------
// Kernel 1: curr = emb[mask_curr_traj_grid] + pe[:128]
// grid: B*S_CURR blocks of 256 threads; each thread does 2 elems (sin/cos pair)
// ---------------------------------------------------------------------------
__global__ __launch_bounds__(256) void build_curr(const int* __restrict__ idx,
                                                  const float* __restrict__ emb,
                                                  float* __restrict__ curr) {
    int bs = blockIdx.x;             // b*128 + s
    int s  = bs & (S_CURR - 1);
    int g  = idx[bs];
    const float* e = emb + (size_t)g * D;
    float* o = curr + (size_t)bs * D;
    int d = threadIdx.x * 2;         // even dim
    // div_term[i] = exp(-(2i) * ln(10000)/512), here 2i == d
    float div = expf(-(float)d * (9.210340371976184f / 512.0f));
    float ang = (float)s * div;
    o[d]     = e[d]     + sinf(ang);
    o[d + 1] = e[d + 1] + cosf(ang);
}

// ---------------------------------------------------------------------------
// Generic C = A @ B^T (+bias), K = 512 fixed, bf16 MFMA 16x16x32.
// A: M x 512 f32 row-major  (optionally tanh applied)
// Bt: Nrows x 512 f32 row-major (rows are output columns)
// C: M x ldc f32
// Block tile 128x128, 256 threads = 4 waves (2x2), each wave 64x64 (4x4 MFMA).
// grid: (M/128, ceil(N/128))
// ---------------------------------------------------------------------------
#define LDA 40  // 32 + 8 bf16 pad

__global__ __launch_bounds__(256) void gemm_abt(const float* __restrict__ A,
                                                const float* __restrict__ Bt,
                                                const float* __restrict__ bias,
                                                float* __restrict__ C,
                                                int M, int Nrows, int ldc,
                                                int tanhA) {
    __shared__ __bf16 As[128 * LDA];
    __shared__ __bf16 Bs[128 * LDA];

    const int tid  = threadIdx.x;
    const int lane = tid & 63;
    const int wave = tid >> 6;
    const int wy   = wave >> 1;      // wave m index (0..1)
    const int wx   = wave & 1;       // wave n index (0..1)
    const int m0   = blockIdx.x * 128;
    const int n0   = blockIdx.y * 128;

    f32x4_t acc[4][4];
#pragma unroll
    for (int i = 0; i < 4; ++i)
#pragma unroll
        for (int j = 0; j < 4; ++j) acc[i][j] = (f32x4_t){0.f, 0.f, 0.f, 0.f};

    const int srow = tid >> 3;        // 0..31
    const int scol = (tid & 7) * 4;   // 0..28 step 4 (floats)

    for (int kk = 0; kk < 512; kk += 32) {
#pragma unroll
        for (int p = 0; p < 4; ++p) {
            int row = srow + p * 32;
            // ---- A tile ----
            int am = m0 + row;
            float4 av = make_float4(0.f, 0.f, 0.f, 0.f);
            if (am < M) av = *(const float4*)(A + (size_t)am * 512 + kk + scol);
            if (tanhA) {
                av.x = tanhf(av.x); av.y = tanhf(av.y);
                av.z = tanhf(av.z); av.w = tanhf(av.w);
            }
            bf16x4_t at;
            at[0] = (__bf16)av.x; at[1] = (__bf16)av.y;
            at[2] = (__bf16)av.z; at[3] = (__bf16)av.w;
            *(bf16x4_t*)&As[row * LDA + scol] = at;
            // ---- B tile ----
            int bn = n0 + row;
            float4 bv = make_float4(0.f, 0.f, 0.f, 0.f);
            if (bn < Nrows) bv = *(const float4*)(Bt + (size_t)bn * 512 + kk + scol);
            bf16x4_t bt;
            bt[0] = (__bf16)bv.x; bt[1] = (__bf16)bv.y;
            bt[2] = (__bf16)bv.z; bt[3] = (__bf16)bv.w;
            *(bf16x4_t*)&Bs[row * LDA + scol] = bt;
        }
        __syncthreads();

        const int kb = (lane >> 4) * 8;
        bf16x8_t af[4], bfr[4];
#pragma unroll
        for (int i = 0; i < 4; ++i) {
            int row = wy * 64 + i * 16 + (lane & 15);
            af[i] = *(const bf16x8_t*)&As[row * LDA + kb];
        }
#pragma unroll
        for (int j = 0; j < 4; ++j) {
            int col = wx * 64 + j * 16 + (lane & 15);
            bfr[j] = *(const bf16x8_t*)&Bs[col * LDA + kb];
        }
#pragma unroll
        for (int i = 0; i < 4; ++i)
#pragma unroll
            for (int j = 0; j < 4; ++j)
                acc[i][j] = __builtin_amdgcn_mfma_f32_16x16x32_bf16(
                    af[i], bfr[j], acc[i][j], 0, 0, 0);
        __syncthreads();
    }

    // Epilogue: C/D layout col = lane&15, row = (lane>>4)*4 + r
#pragma unroll
    for (int i = 0; i < 4; ++i) {
#pragma unroll
        for (int j = 0; j < 4; ++j) {
            int col = n0 + wx * 64 + j * 16 + (lane & 15);
            if (col >= Nrows) continue;
            float bv = bias ? bias[col] : 0.f;
#pragma unroll
            for (int r = 0; r < 4; ++r) {
                int row = m0 + wy * 64 + i * 16 + (lane >> 4) * 4 + r;
                if (row < M) C[(size_t)row * ldc + col] = acc[i][j][r] + bv;
            }
        }
    }
}

// ---------------------------------------------------------------------------
// Kernel 3: attention at gathered positions only.
// grid (512, 8): block = (row r = b*16+n, head h); 128 threads.
// scores s_t = q . K[b,t,h]; softmax over t (128); out = sum p_t V[b,t,h].
// No 1/sqrt(dh) scaling (matches reference).
// ---------------------------------------------------------------------------
__global__ __launch_bounds__(128) void attn_kernel(const float* __restrict__ Q,
                                                   const float* __restrict__ K,
                                                   const float* __restrict__ V,
                                                   const int* __restrict__ mask_pos,
                                                   float* __restrict__ attn_out) {
    int r = blockIdx.x;      // 0..511
    int h = blockIdx.y;      // 0..7
    int b = r >> 4;
    int t = threadIdx.x;     // 0..127

    __shared__ float qv[DH];
    __shared__ float p[S_CURR];
    __shared__ float red[S_CURR];

    int pos = mask_pos[r];
    if (t < DH) qv[t] = Q[((size_t)(b * S_CURR + pos)) * D + h * DH + t];
    __syncthreads();

    const float* Krow = K + ((size_t)(b * S_CURR + t)) * D + h * DH;
    float s = 0.f;
#pragma unroll
    for (int d = 0; d < DH; d += 4) {
        float4 kv = *(const float4*)(Krow + d);
        s += qv[d] * kv.x + qv[d + 1] * kv.y + qv[d + 2] * kv.z + qv[d + 3] * kv.w;
    }
    red[t] = s;
    __syncthreads();
    for (int off = 64; off > 0; off >>= 1) {
        if (t < off) red[t] = fmaxf(red[t], red[t + off]);
        __syncthreads();
    }
    float m = red[0];
    __syncthreads();
    float e = expf(s - m);
    p[t] = e;
    red[t] = e;
    __syncthreads();
    for (int off = 64; off > 0; off >>= 1) {
        if (t < off) red[t] += red[t + off];
        __syncthreads();
    }
    float inv = 1.0f / red[0];
    __syncthreads();

    // out[d] = sum_t p[t] * V[b,t,h*64+d]; 2 threads per d
    int d = t & 63, half = t >> 6;
    float acc = 0.f;
    for (int kkk = half * 64; kkk < half * 64 + 64; ++kkk)
        acc += p[kkk] * V[((size_t)(b * S_CURR + kkk)) * D + h * DH + d];
    red[t] = acc;
    __syncthreads();
    if (t < 64)
        attn_out[(size_t)r * D + h * DH + d] = (red[t] + red[t + 64]) * inv;
}

// ---------------------------------------------------------------------------
// Kernel 6: row-wise log_softmax. One block per row (512), 256 threads.
// Online max/sum in one streaming pass, then write out (unpadded stride).
// ---------------------------------------------------------------------------
__global__ __launch_bounds__(256) void logsoftmax_kernel(const float* __restrict__ scores,
                                                         float* __restrict__ out) {
    int r = blockIdx.x;
    const float* srow = scores + (size_t)r * SCORE_LD;
    float m = -INFINITY, ssum = 0.f;
    for (int i = threadIdx.x; i < NCAND; i += 256) {
        float x = srow[i];
        if (x > m) {
            ssum = ssum * expf(m - x) + 1.0f;
            m = x;
        } else {
            ssum += expf(x - m);
        }
    }
    __shared__ float ms[256], ss[256];
    ms[threadIdx.x] = m; ss[threadIdx.x] = ssum;
    __syncthreads();
    for (int off = 128; off > 0; off >>= 1) {
        if (threadIdx.x < off) {
            float m1 = ms[threadIdx.x], s1 = ss[threadIdx.x];
            float m2 = ms[threadIdx.x + off], s2 = ss[threadIdx.x + off];
            float mm = fmaxf(m1, m2);
            ms[threadIdx.x] = mm;
            ss[threadIdx.x] = s1 * expf(m1 - mm) + s2 * expf(m2 - mm);
        }
        __syncthreads();
    }
    float lse = ms[0] + logf(ss[0]);
    float* orow = out + (size_t)r * NCAND;
    for (int i = threadIdx.x; i < NCAND; i += 256)
        orow[i] = srow[i] - lse;
}

// ---------------------------------------------------------------------------
extern "C" void kernel_launch(void* const* d_in, const int* in_sizes, int n_in,
                              void* d_out, int out_size, void* d_ws, size_t ws_size,
                              hipStream_t stream) {
    const int*   mask_pos = (const int*)d_in[2];
    const int*   curr_idx = (const int*)d_in[3];
    const float* emb      = (const float*)d_in[5];
    const float* c_wq = (const float*)d_in[12];
    const float* c_bq = (const float*)d_in[13];
    const float* c_wk = (const float*)d_in[14];
    const float* c_bk = (const float*)d_in[15];
    const float* c_wv = (const float*)d_in[16];
    const float* c_bv = (const float*)d_in[17];
    const float* t2_w = (const float*)d_in[24];
    const float* t2_b = (const float*)d_in[25];
    float* out = (float*)d_out;

    float* ws = (float*)d_ws;
    // scores occupies [0, 512*SCORE_LD); curr/Q/K/V live inside it (dead
    // before scores is written). attn_g / gathered live past the end.
    float* scores   = ws;
    float* curr     = ws;                       // 32*128*512 = 2,097,152
    float* Qf       = ws + 2097152;             // 2,097,152
    float* Kf       = ws + 2 * 2097152;         // 2,097,152
    float* Vf       = ws + 3 * 2097152;         // 2,097,152
    float* attn_g   = ws + (size_t)512 * SCORE_LD;        // 262,144
    float* gathered = attn_g + 262144;                    // 262,144
    // total ws use: (512*40064 + 2*262144)*4 = 84,148,224 bytes

    // 1. curr = emb[idx] + pe
    hipLaunchKernelGGL(build_curr, dim3(B * S_CURR), dim3(256), 0, stream,
                       curr_idx, emb, curr);
    // 2-4. Q/K/V projections (M=4096, N=512)
    hipLaunchKernelGGL(gemm_abt, dim3(32, 4), dim3(256), 0, stream,
                       curr, c_wq, c_bq, Qf, 4096, 512, 512, 0);
    hipLaunchKernelGGL(gemm_abt, dim3(32, 4), dim3(256), 0, stream,
                       curr, c_wk, c_bk, Kf, 4096, 512, 512, 0);
    hipLaunchKernelGGL(gemm_abt, dim3(32, 4), dim3(256), 0, stream,
                       curr, c_wv, c_bv, Vf, 4096, 512, 512, 0);
    // 5. attention at the 512 gathered (b,pos) rows
    hipLaunchKernelGGL(attn_kernel, dim3(MG, H), dim3(128), 0, stream,
                       Qf, Kf, Vf, mask_pos, attn_g);
    // 6. gathered = tanh(attn_g) @ t2_w^T + t2_b   (M=512, N=512)
    hipLaunchKernelGGL(gemm_abt, dim3(4, 4), dim3(256), 0, stream,
                       attn_g, t2_w, t2_b, gathered, 512, 512, 512, 1);
    // 7. scores = gathered @ emb[2:]^T   (M=512, N=39998)
    hipLaunchKernelGGL(gemm_abt, dim3(4, 313), dim3(256), 0, stream,
                       gathered, emb + 2 * D, (const float*)nullptr, scores,
                       512, NCAND, SCORE_LD, 0);
    // 8. log_softmax rows -> out
    hipLaunchKernelGGL(logsoftmax_kernel, dim3(MG), dim3(256), 0, stream,
                       scores, out);
}

// Round 2
// 341.817 us; speedup vs baseline: 1.9914x; 1.9914x over previous
//
#include <hip/hip_runtime.h>
#include <hip/hip_bf16.h>
#include <math.h>
#include <float.h>

#define B       32
#define S_CURR  128
#define D       512
#define H       8
#define DH      64
#define NM      16
#define NCAND   39998          // emb[2:]
#define MG      (B * NM)       // 512 gathered rows
#define SCLD    40064          // padded col stride of bf16 score buffer
#define NT      313            // ceil(NCAND/128) N-tiles

typedef __bf16 bf16x8_t __attribute__((ext_vector_type(8)));
typedef float  f32x4_t  __attribute__((ext_vector_type(4)));

typedef __attribute__((address_space(3))) unsigned int lds_u32_t;
typedef const __attribute__((address_space(1))) unsigned int gbl_u32_t;

__device__ __forceinline__ void async16(const void* g, void* l) {
    // lane L of the wave reads 16B at its own g and lands at (uniform l) + L*16
    __builtin_amdgcn_global_load_lds((gbl_u32_t*)g, (lds_u32_t*)l, 16, 0, 0);
}

// ---------------------------------------------------------------------------
// convert f32 -> bf16: emb[2:] (blocks 0..9999) and 4 weight mats (128 blocks ea)
// ---------------------------------------------------------------------------
__global__ __launch_bounds__(256) void convert_all(
    const float* __restrict__ emb,
    const float* __restrict__ wq, const float* __restrict__ wk,
    const float* __restrict__ wv, const float* __restrict__ t2w,
    __bf16* __restrict__ embB, __bf16* __restrict__ wqB, __bf16* __restrict__ wkB,
    __bf16* __restrict__ wvB, __bf16* __restrict__ t2wB)
{
    int bx = blockIdx.x;
    const float* src; __bf16* dst; size_t n, base;
    if (bx < 10000) {
        src = emb + 2 * D; dst = embB; n = (size_t)NCAND * D; base = (size_t)bx * 2048;
    } else {
        int w = (bx - 10000) >> 7;
        base = (size_t)((bx - 10000) & 127) * 2048;
        n = (size_t)D * D;
        src = (w == 0) ? wq : (w == 1) ? wk : (w == 2) ? wv : t2w;
        dst = (w == 0) ? wqB : (w == 1) ? wkB : (w == 2) ? wvB : t2wB;
    }
    size_t i = base + (size_t)threadIdx.x * 8;
    if (i >= n) return;
    float4 a = *(const float4*)(src + i);
    float4 b = *(const float4*)(src + i + 4);
    bf16x8_t v;
    v[0] = (__bf16)a.x; v[1] = (__bf16)a.y; v[2] = (__bf16)a.z; v[3] = (__bf16)a.w;
    v[4] = (__bf16)b.x; v[5] = (__bf16)b.y; v[6] = (__bf16)b.z; v[7] = (__bf16)b.w;
    *(bf16x8_t*)(dst + i) = v;
}

// ---------------------------------------------------------------------------
// currB = bf16(emb[idx] + pe); block 4096 computes qidx[r] = b*128 + mask_pos[r]
// ---------------------------------------------------------------------------
__global__ __launch_bounds__(256) void build_curr(const int* __restrict__ idx,
                                                  const float* __restrict__ emb,
                                                  __bf16* __restrict__ currB,
                                                  const int* __restrict__ mask_pos,
                                                  int* __restrict__ qidx) {
    int bs = blockIdx.x;
    if (bs == B * S_CURR) {
        int r = threadIdx.x;
        qidx[r] = (r >> 4) * S_CURR + mask_pos[r];
        r += 256;
        qidx[r] = (r >> 4) * S_CURR + mask_pos[r];
        return;
    }
    int s = bs & (S_CURR - 1);
    int g = idx[bs];
    const float* e = emb + (size_t)g * D;
    __bf16* o = currB + (size_t)bs * D;
    int d = threadIdx.x * 2;
    float div = expf(-(float)d * (9.210340371976184f / 512.0f));
    float ang = (float)s * div;
    o[d]     = (__bf16)(e[d]     + sinf(ang));
    o[d + 1] = (__bf16)(e[d + 1] + cosf(ang));
}

// ---------------------------------------------------------------------------
// bf16 GEMM, m97 structure: C = A @ W^T + bias, K=512, N=512 fixed.
// Tile 128x128, BK=64, 4 waves (2x2), global_load_lds width-16 staging,
// unpadded LDS [128][64], ds_read_b128 fragments, MFMA 16x16x32.
// blockIdx.z selects (W0,b0,C0) vs (W1,b1,C1). rowidx optionally gathers A rows.
// ---------------------------------------------------------------------------
__global__ __launch_bounds__(256) void gemm_bf(
    const __bf16* __restrict__ A,
    const __bf16* __restrict__ W0, const float* __restrict__ b0, __bf16* __restrict__ C0,
    const __bf16* __restrict__ W1, const float* __restrict__ b1, __bf16* __restrict__ C1,
    const int* __restrict__ rowidx)
{
    const __bf16* W = blockIdx.z ? W1 : W0;
    const float* bias = blockIdx.z ? b1 : b0;
    __bf16* C = blockIdx.z ? C1 : C0;

    __shared__ __bf16 As[128 * 64];
    __shared__ __bf16 Bs[128 * 64];

    const int tid = threadIdx.x, lane = tid & 63, wave = tid >> 6;
    const int wy = wave >> 1, wx = wave & 1;
    const int m0 = blockIdx.x * 128, n0 = blockIdx.y * 128;
    const int lrow = lane >> 3, lcol = (lane & 7) * 8;

    const __bf16* aptr[4]; const __bf16* bptr[4];
#pragma unroll
    for (int i = 0; i < 4; ++i) {
        int chunk = wave * 4 + i;
        int ar = m0 + chunk * 8 + lrow;
        if (rowidx) ar = rowidx[ar];
        aptr[i] = A + (size_t)ar * 512 + lcol;
        bptr[i] = W + (size_t)(n0 + chunk * 8 + lrow) * 512 + lcol;
    }

    f32x4_t acc[4][4];
#pragma unroll
    for (int i = 0; i < 4; ++i)
#pragma unroll
        for (int j = 0; j < 4; ++j) acc[i][j] = (f32x4_t){0.f, 0.f, 0.f, 0.f};

    for (int kk = 0; kk < 512; kk += 64) {
#pragma unroll
        for (int i = 0; i < 4; ++i) {
            int chunk = wave * 4 + i;
            async16(aptr[i] + kk, &As[chunk * 512]);
            async16(bptr[i] + kk, &Bs[chunk * 512]);
        }
        __syncthreads();
#pragma unroll
        for (int kb = 0; kb < 2; ++kb) {
            const int ko = kb * 32 + (lane >> 4) * 8;
            bf16x8_t af[4], bfv[4];
#pragma unroll
            for (int i = 0; i < 4; ++i)
                af[i] = *(const bf16x8_t*)&As[(wy * 64 + i * 16 + (lane & 15)) * 64 + ko];
#pragma unroll
            for (int j = 0; j < 4; ++j)
                bfv[j] = *(const bf16x8_t*)&Bs[(wx * 64 + j * 16 + (lane & 15)) * 64 + ko];
#pragma unroll
            for (int i = 0; i < 4; ++i)
#pragma unroll
                for (int j = 0; j < 4; ++j)
                    acc[i][j] = __builtin_amdgcn_mfma_f32_16x16x32_bf16(
                        af[i], bfv[j], acc[i][j], 0, 0, 0);
        }
        __syncthreads();
    }

    const int colq = lane & 15, quad = lane >> 4;
#pragma unroll
    for (int i = 0; i < 4; ++i)
#pragma unroll
        for (int j = 0; j < 4; ++j) {
            int col = n0 + wx * 64 + j * 16 + colq;
            float bv = bias[col];
#pragma unroll
            for (int rr = 0; rr < 4; ++rr) {
                int row = m0 + wy * 64 + i * 16 + quad * 4 + rr;
                C[(size_t)row * 512 + col] = (__bf16)(acc[i][j][rr] + bv);
            }
        }
}

// ---------------------------------------------------------------------------
// Scores GEMM: scB[512 x NCAND] = gatheredB @ embB^T (bf16 store) + per-block
// streaming-softmax partials (pmax/psum per [ntile][row]).
// grid (4, 313): blockIdx.x = M-tile (fastest -> B-tile L2/LLC sharing).
// ---------------------------------------------------------------------------
__global__ __launch_bounds__(256) void gemm_scores(
    const __bf16* __restrict__ A,      // 512 x 512
    const __bf16* __restrict__ Bm,     // 40064(pad) x 512
    __bf16* __restrict__ scB,          // 512 x SCLD
    float* __restrict__ pmax, float* __restrict__ psum)
{
    __shared__ __bf16 As[128 * 64];
    __shared__ __bf16 Bs[128 * 64];
    __shared__ float redm[2][128], reds[2][128];

    const int tid = threadIdx.x, lane = tid & 63, wave = tid >> 6;
    const int wy = wave >> 1, wx = wave & 1;
    const int m0 = blockIdx.x * 128, n0 = blockIdx.y * 128;
    const int lrow = lane >> 3, lcol = (lane & 7) * 8;

    const __bf16* aptr[4]; const __bf16* bptr[4];
#pragma unroll
    for (int i = 0; i < 4; ++i) {
        int chunk = wave * 4 + i;
        aptr[i] = A + (size_t)(m0 + chunk * 8 + lrow) * 512 + lcol;
        bptr[i] = Bm + (size_t)(n0 + chunk * 8 + lrow) * 512 + lcol;
    }

    f32x4_t acc[4][4];
#pragma unroll
    for (int i = 0; i < 4; ++i)
#pragma unroll
        for (int j = 0; j < 4; ++j) acc[i][j] = (f32x4_t){0.f, 0.f, 0.f, 0.f};

    for (int kk = 0; kk < 512; kk += 64) {
#pragma unroll
        for (int i = 0; i < 4; ++i) {
            int chunk = wave * 4 + i;
            async16(aptr[i] + kk, &As[chunk * 512]);
            async16(bptr[i] + kk, &Bs[chunk * 512]);
        }
        __syncthreads();
#pragma unroll
        for (int kb = 0; kb < 2; ++kb) {
            const int ko = kb * 32 + (lane >> 4) * 8;
            bf16x8_t af[4], bfv[4];
#pragma unroll
            for (int i = 0; i < 4; ++i)
                af[i] = *(const bf16x8_t*)&As[(wy * 64 + i * 16 + (lane & 15)) * 64 + ko];
#pragma unroll
            for (int j = 0; j < 4; ++j)
                bfv[j] = *(const bf16x8_t*)&Bs[(wx * 64 + j * 16 + (lane & 15)) * 64 + ko];
#pragma unroll
            for (int i = 0; i < 4; ++i)
#pragma unroll
                for (int j = 0; j < 4; ++j)
                    acc[i][j] = __builtin_amdgcn_mfma_f32_16x16x32_bf16(
                        af[i], bfv[j], acc[i][j], 0, 0, 0);
        }
        __syncthreads();
    }

    const int colq = lane & 15, quad = lane >> 4;
#pragma unroll
    for (int i = 0; i < 4; ++i) {
#pragma unroll
        for (int rr = 0; rr < 4; ++rr) {
            const int row = wy * 64 + i * 16 + quad * 4 + rr;   // local row
            const size_t rowbase = (size_t)(m0 + row) * SCLD;
            float v[4]; float m = -FLT_MAX;
#pragma unroll
            for (int j = 0; j < 4; ++j) {
                int col = n0 + wx * 64 + j * 16 + colq;
                __bf16 xb = (__bf16)acc[i][j][rr];
                if (col < NCAND) {
                    scB[rowbase + col] = xb;
                    float xr = (float)xb;
                    v[j] = xr; m = fmaxf(m, xr);
                } else v[j] = -FLT_MAX;
            }
            float s = 0.f;
#pragma unroll
            for (int j = 0; j < 4; ++j)
                s += (v[j] > -FLT_MAX) ? __expf(v[j] - m) : 0.f;
            // merge across the 16 column-lanes of this quad group
#pragma unroll
            for (int mk = 1; mk < 16; mk <<= 1) {
                float om = __shfl_xor(m, mk);
                float os = __shfl_xor(s, mk);
                float mm = fmaxf(m, om);
                s = s * __expf(m - mm) + os * __expf(om - mm);
                m = mm;
            }
            if (colq == 0) { redm[wx][row] = m; reds[wx][row] = s; }
        }
    }
    __syncthreads();
    if (tid < 128) {
        float ma = redm[0][tid], sa = reds[0][tid];
        float mb = redm[1][tid], sb = reds[1][tid];
        float mm = fmaxf(ma, mb);
        float ss = sa * __expf(ma - mm) + sb * __expf(mb - mm);
        pmax[(size_t)blockIdx.y * MG + m0 + tid] = mm;
        psum[(size_t)blockIdx.y * MG + m0 + tid] = ss;
    }
}

// ---------------------------------------------------------------------------
// Attention at the 512 gathered rows; tanh fused at the output write.
// grid (512, 8), 128 threads.
// ---------------------------------------------------------------------------
__global__ __launch_bounds__(128) void attn_kernel(const __bf16* __restrict__ Q,
                                                   const __bf16* __restrict__ K,
                                                   const __bf16* __restrict__ V,
                                                   __bf16* __restrict__ attnB) {
    int r = blockIdx.x, h = blockIdx.y, b = r >> 4, t = threadIdx.x;

    __shared__ float qv[DH];
    __shared__ float p[S_CURR];
    __shared__ float red[S_CURR];

    if (t < DH) qv[t] = (float)Q[(size_t)r * D + h * DH + t];
    __syncthreads();

    const __bf16* Krow = K + ((size_t)(b * S_CURR + t)) * D + h * DH;
    float s = 0.f;
#pragma unroll
    for (int d = 0; d < DH; d += 8) {
        bf16x8_t kv = *(const bf16x8_t*)(Krow + d);
#pragma unroll
        for (int q = 0; q < 8; ++q) s += qv[d + q] * (float)kv[q];
    }
    red[t] = s;
    __syncthreads();
    for (int off = 64; off > 0; off >>= 1) {
        if (t < off) red[t] = fmaxf(red[t], red[t + off]);
        __syncthreads();
    }
    float m = red[0];
    __syncthreads();
    float e = __expf(s - m);
    p[t] = e; red[t] = e;
    __syncthreads();
    for (int off = 64; off > 0; off >>= 1) {
        if (t < off) red[t] += red[t + off];
        __syncthreads();
    }
    float inv = 1.0f / red[0];
    __syncthreads();

    int d = t & 63, half = t >> 6;
    float acc = 0.f;
    for (int k2 = half * 64; k2 < half * 64 + 64; ++k2)
        acc += p[k2] * (float)V[((size_t)(b * S_CURR + k2)) * D + h * DH + d];
    red[t] = acc;
    __syncthreads();
    if (t < 64)
        attnB[(size_t)r * D + h * DH + d] = (__bf16)tanhf((red[t] + red[t + 64]) * inv);
}

// ---------------------------------------------------------------------------
// lse[row] = streaming merge of 313 (max,sum) partials
// ---------------------------------------------------------------------------
__global__ __launch_bounds__(256) void lse_reduce(const float* __restrict__ pmax,
                                                  const float* __restrict__ psum,
                                                  float* __restrict__ lse) {
    int row = blockIdx.x, t = threadIdx.x;
    float m = -FLT_MAX, s = 0.f;
    for (int i = t; i < NT; i += 256) {
        float om = pmax[(size_t)i * MG + row];
        float os = psum[(size_t)i * MG + row];
        float mm = fmaxf(m, om);
        s = s * __expf(m - mm) + os * __expf(om - mm);
        m = mm;
    }
    __shared__ float ms[256], ss[256];
    ms[t] = m; ss[t] = s;
    __syncthreads();
    for (int off = 128; off > 0; off >>= 1) {
        if (t < off) {
            float m1 = ms[t], s1 = ss[t], m2 = ms[t + off], s2 = ss[t + off];
            float mm = fmaxf(m1, m2);
            ms[t] = mm;
            ss[t] = s1 * __expf(m1 - mm) + s2 * __expf(m2 - mm);
        }
        __syncthreads();
    }
    if (t == 0) lse[row] = ms[0] + logf(ss[0]);
}

// ---------------------------------------------------------------------------
// out[row, c] = (float)scB[row, c] - lse[row]
// ---------------------------------------------------------------------------
__global__ __launch_bounds__(256) void final_out(const __bf16* __restrict__ scB,
                                                 const float* __restrict__ lse,
                                                 float* __restrict__ out) {
    int row = blockIdx.y;
    int c0 = (blockIdx.x * 256 + threadIdx.x) * 8;
    if (c0 >= NCAND) return;
    float l = lse[row];
    bf16x8_t v = *(const bf16x8_t*)(scB + (size_t)row * SCLD + c0);
    float* o = out + (size_t)row * NCAND + c0;
    if (c0 + 8 <= NCAND) {
        *(float2*)(o)     = make_float2((float)v[0] - l, (float)v[1] - l);
        *(float2*)(o + 2) = make_float2((float)v[2] - l, (float)v[3] - l);
        *(float2*)(o + 4) = make_float2((float)v[4] - l, (float)v[5] - l);
        *(float2*)(o + 6) = make_float2((float)v[6] - l, (float)v[7] - l);
    } else {
        for (int k2 = 0; k2 < NCAND - c0; ++k2) o[k2] = (float)v[k2] - l;
    }
}

// ---------------------------------------------------------------------------
extern "C" void kernel_launch(void* const* d_in, const int* in_sizes, int n_in,
                              void* d_out, int out_size, void* d_ws, size_t ws_size,
                              hipStream_t stream) {
    const int*   mask_pos = (const int*)d_in[2];
    const int*   curr_idx = (const int*)d_in[3];
    const float* emb      = (const float*)d_in[5];
    const float* c_bq = (const float*)d_in[13];
    const float* c_wq = (const float*)d_in[12];
    const float* c_wk = (const float*)d_in[14];
    const float* c_bk = (const float*)d_in[15];
    const float* c_wv = (const float*)d_in[16];
    const float* c_bv = (const float*)d_in[17];
    const float* t2_w = (const float*)d_in[24];
    const float* t2_b = (const float*)d_in[25];
    float* out = (float*)d_out;

    char* w = (char*)d_ws;
    // [0, 41,025,536)            embB   (40064 padded rows x 512 bf16)
    // [41,025,536, 82,051,072)   scB    (512 x 40064 bf16) -- overlays the
    //                            pre-scores temporaries below (dead by then):
    __bf16* embB  = (__bf16*)w;
    __bf16* scB   = (__bf16*)(w + 41025536);
    __bf16* currB = scB;                                  // 4 MB
    __bf16* Kf    = (__bf16*)(w + 41025536 + 4194304);    // 4 MB
    __bf16* Vf    = (__bf16*)(w + 41025536 + 8388608);    // 4 MB
    __bf16* Qg    = (__bf16*)(w + 41025536 + 12582912);   // 0.5 MB
    __bf16* attnB = (__bf16*)(w + 41025536 + 13107200);   // 0.5 MB
    __bf16* wqB   = (__bf16*)(w + 41025536 + 13631488);
    __bf16* wkB   = (__bf16*)(w + 41025536 + 14155776);
    __bf16* wvB   = (__bf16*)(w + 41025536 + 14680064);
    __bf16* t2wB  = (__bf16*)(w + 41025536 + 15204352);
    int*    qidx  = (int*)   (w + 41025536 + 15728640);
    __bf16* gatheredB = (__bf16*)(w + 82051072);          // 0.5 MB
    float*  pmax  = (float*)(w + 82575360);               // 313*512 f32
    float*  psum  = (float*)(w + 83216384);               // 313*512 f32
    float*  lse   = (float*)(w + 83857408);               // 512 f32

    hipLaunchKernelGGL(convert_all, dim3(10512), dim3(256), 0, stream,
                       emb, c_wq, c_wk, c_wv, t2_w, embB, wqB, wkB, wvB, t2wB);
    hipLaunchKernelGGL(build_curr, dim3(B * S_CURR + 1), dim3(256), 0, stream,
                       curr_idx, emb, currB, mask_pos, qidx);
    // Q projection only at gathered rows (M=512, rowidx gather)
    hipLaunchKernelGGL(gemm_bf, dim3(4, 4, 1), dim3(256), 0, stream,
                       currB, wqB, c_bq, Qg, wqB, c_bq, Qg, qidx);
    // K and V projections fused via grid.z (M=4096 each)
    hipLaunchKernelGGL(gemm_bf, dim3(32, 4, 2), dim3(256), 0, stream,
                       currB, wkB, c_bk, Kf, wvB, c_bv, Vf, (const int*)nullptr);
    hipLaunchKernelGGL(attn_kernel, dim3(MG, H), dim3(128), 0, stream,
                       Qg, Kf, Vf, attnB);
    // gathered = tanh(attn) @ t2_w^T + t2_b (tanh already applied)
    hipLaunchKernelGGL(gemm_bf, dim3(4, 4, 1), dim3(256), 0, stream,
                       attnB, t2wB, t2_b, gatheredB, t2wB, t2_b, gatheredB,
                       (const int*)nullptr);
    hipLaunchKernelGGL(gemm_scores, dim3(4, NT), dim3(256), 0, stream,
                       gatheredB, embB, scB, pmax, psum);
    hipLaunchKernelGGL(lse_reduce, dim3(MG), dim3(256), 0, stream, pmax, psum, lse);
    hipLaunchKernelGGL(final_out, dim3(20, MG), dim3(256), 0, stream, scB, lse, out);
}

// Round 3
// 305.567 us; speedup vs baseline: 2.2277x; 1.1186x over previous
//
#include <hip/hip_runtime.h>
#include <hip/hip_bf16.h>
#include <math.h>
#include <float.h>

#define B       32
#define S_CURR  128
#define D       512
#define H       8
#define DH      64
#define NM      16
#define NCAND   39998          // emb[2:]
#define MG      (B * NM)       // 512 gathered rows
#define SCLD    40064          // padded row count of embB / col stride of scB
#define NT      313            // ceil(NCAND/128) N-tiles

typedef __bf16 bf16x8_t __attribute__((ext_vector_type(8)));
typedef float  f32x4_t  __attribute__((ext_vector_type(4)));

typedef __attribute__((address_space(3))) unsigned int lds_u32_t;
typedef const __attribute__((address_space(1))) unsigned int gbl_u32_t;

__device__ __forceinline__ void async16(const void* g, void* l) {
    __builtin_amdgcn_global_load_lds((gbl_u32_t*)g, (lds_u32_t*)l, 16, 0, 0);
}

// ---------------------------------------------------------------------------
// Prep kernel: bx < 10512 -> f32->bf16 converts (emb[2:], 4 weight mats);
// 10512 <= bx < 14608 -> currB = bf16(emb[idx]+pe); bx == 14608 -> qidx.
// ---------------------------------------------------------------------------
__global__ __launch_bounds__(256) void prep_kernel(
    const float* __restrict__ emb,
    const float* __restrict__ wq, const float* __restrict__ wk,
    const float* __restrict__ wv, const float* __restrict__ t2w,
    __bf16* __restrict__ embB, __bf16* __restrict__ wqB, __bf16* __restrict__ wkB,
    __bf16* __restrict__ wvB, __bf16* __restrict__ t2wB,
    const int* __restrict__ curr_idx, __bf16* __restrict__ currB,
    const int* __restrict__ mask_pos, int* __restrict__ qidx)
{
    int bx = blockIdx.x;
    if (bx < 10512) {
        const float* src; __bf16* dst; size_t n, base;
        if (bx < 10000) {
            src = emb + 2 * D; dst = embB; n = (size_t)NCAND * D; base = (size_t)bx * 2048;
        } else {
            int w = (bx - 10000) >> 7;
            base = (size_t)((bx - 10000) & 127) * 2048;
            n = (size_t)D * D;
            src = (w == 0) ? wq : (w == 1) ? wk : (w == 2) ? wv : t2w;
            dst = (w == 0) ? wqB : (w == 1) ? wkB : (w == 2) ? wvB : t2wB;
        }
        size_t i = base + (size_t)threadIdx.x * 8;
        if (i >= n) return;
        float4 a = *(const float4*)(src + i);
        float4 b = *(const float4*)(src + i + 4);
        bf16x8_t v;
        v[0] = (__bf16)a.x; v[1] = (__bf16)a.y; v[2] = (__bf16)a.z; v[3] = (__bf16)a.w;
        v[4] = (__bf16)b.x; v[5] = (__bf16)b.y; v[6] = (__bf16)b.z; v[7] = (__bf16)b.w;
        *(bf16x8_t*)(dst + i) = v;
        return;
    }
    if (bx == 14608) {
        int r = threadIdx.x;
        qidx[r] = (r >> 4) * S_CURR + mask_pos[r];
        r += 256;
        qidx[r] = (r >> 4) * S_CURR + mask_pos[r];
        return;
    }
    int bs = bx - 10512;
    int s = bs & (S_CURR - 1);
    int g = curr_idx[bs];
    const float* e = emb + (size_t)g * D;
    __bf16* o = currB + (size_t)bs * D;
    int d = threadIdx.x * 2;
    float div = expf(-(float)d * (9.210340371976184f / 512.0f));
    float ang = (float)s * div;
    o[d]     = (__bf16)(e[d]     + sinf(ang));
    o[d + 1] = (__bf16)(e[d + 1] + cosf(ang));
}

// ---------------------------------------------------------------------------
// bf16 GEMM, swizzled-LDS m97 structure: C = A @ W^T + bias, K=512, N=512.
// LDS granule swizzle: logical (row, kgrp) lives at elem row*64 + (kgrp^(row&7))*8.
// Staging stays wave-contiguous (global_load_lds-compatible) by permuting the
// global column each lane fetches. grid.z selects {K, V, Q(gathered)} problems.
// ---------------------------------------------------------------------------
__global__ __launch_bounds__(256) void gemm_bf(
    const __bf16* __restrict__ A,
    const __bf16* __restrict__ W0, const float* __restrict__ b0, __bf16* __restrict__ C0,
    const __bf16* __restrict__ W1, const float* __restrict__ b1, __bf16* __restrict__ C1,
    const __bf16* __restrict__ W2, const float* __restrict__ b2, __bf16* __restrict__ C2,
    const int* __restrict__ rowidx)
{
    const int z = blockIdx.z;
    if (z == 2 && blockIdx.x >= 4) return;   // Q problem has M=512 only
    const __bf16* W = (z == 0) ? W0 : (z == 1) ? W1 : W2;
    const float* bias = (z == 0) ? b0 : (z == 1) ? b1 : b2;
    __bf16* C = (z == 0) ? C0 : (z == 1) ? C1 : C2;

    __shared__ __bf16 As[128 * 64];
    __shared__ __bf16 Bs[128 * 64];

    const int tid = threadIdx.x, lane = tid & 63, wave = tid >> 6;
    const int wy = wave >> 1, wx = wave & 1;
    const int m0 = blockIdx.x * 128, n0 = blockIdx.y * 128;
    const int lrow = lane >> 3;
    const int lcol = (((lane & 7) ^ lrow) & 7) * 8;   // swizzled source column

    const __bf16* aptr[4]; const __bf16* bptr[4];
#pragma unroll
    for (int i = 0; i < 4; ++i) {
        int chunk = wave * 4 + i;
        int ar = m0 + chunk * 8 + lrow;
        if (z == 2) ar = rowidx[ar];
        aptr[i] = A + (size_t)ar * 512 + lcol;
        bptr[i] = W + (size_t)(n0 + chunk * 8 + lrow) * 512 + lcol;
    }

    f32x4_t acc[4][4];
#pragma unroll
    for (int i = 0; i < 4; ++i)
#pragma unroll
        for (int j = 0; j < 4; ++j) acc[i][j] = (f32x4_t){0.f, 0.f, 0.f, 0.f};

    const int l7 = lane & 7, quad = lane >> 4, c16 = lane & 15;

    for (int kk = 0; kk < 512; kk += 64) {
#pragma unroll
        for (int i = 0; i < 4; ++i) {
            int chunk = wave * 4 + i;
            async16(aptr[i] + kk, &As[chunk * 512]);
            async16(bptr[i] + kk, &Bs[chunk * 512]);
        }
        __syncthreads();
#pragma unroll
        for (int kb = 0; kb < 2; ++kb) {
            const int goff = (((kb * 4 + quad) ^ l7)) * 8;
            bf16x8_t af[4], bfv[4];
#pragma unroll
            for (int i = 0; i < 4; ++i)
                af[i] = *(const bf16x8_t*)&As[(wy * 64 + i * 16 + c16) * 64 + goff];
#pragma unroll
            for (int j = 0; j < 4; ++j)
                bfv[j] = *(const bf16x8_t*)&Bs[(wx * 64 + j * 16 + c16) * 64 + goff];
#pragma unroll
            for (int i = 0; i < 4; ++i)
#pragma unroll
                for (int j = 0; j < 4; ++j)
                    acc[i][j] = __builtin_amdgcn_mfma_f32_16x16x32_bf16(
                        af[i], bfv[j], acc[i][j], 0, 0, 0);
        }
        __syncthreads();
    }

#pragma unroll
    for (int i = 0; i < 4; ++i)
#pragma unroll
        for (int j = 0; j < 4; ++j) {
            int col = n0 + wx * 64 + j * 16 + c16;
            float bv = bias[col];
#pragma unroll
            for (int rr = 0; rr < 4; ++rr) {
                int row = m0 + wy * 64 + i * 16 + quad * 4 + rr;
                C[(size_t)row * 512 + col] = (__bf16)(acc[i][j][rr] + bv);
            }
        }
}

// ---------------------------------------------------------------------------
// Scores GEMM + softmax partials. 1-D grid 1280: xcd = bid&7 owns N-tiles
// [xcd*40, xcd*40+40); its 4 M-tile blocks per N-tile are consecutive in k
// so they co-run on the same XCD and share the B-tile in that XCD's L2.
// ---------------------------------------------------------------------------
__global__ __launch_bounds__(256) void gemm_scores(
    const __bf16* __restrict__ A,      // 512 x 512 (gatheredB)
    const __bf16* __restrict__ Bm,     // 40064(pad) x 512 (embB)
    __bf16* __restrict__ scB,          // 512 x SCLD
    float* __restrict__ pmax, float* __restrict__ psum)
{
    const int bid = blockIdx.x;
    const int xcd = bid & 7, k = bid >> 3;       // k: 0..159
    const int nt = xcd * 40 + (k >> 2);
    if (nt >= NT) return;
    const int m0 = (k & 3) * 128, n0 = nt * 128;

    __shared__ __bf16 As[128 * 64];
    __shared__ __bf16 Bs[128 * 64];
    __shared__ float redm[2][128], reds[2][128];

    const int tid = threadIdx.x, lane = tid & 63, wave = tid >> 6;
    const int wy = wave >> 1, wx = wave & 1;
    const int lrow = lane >> 3;
    const int lcol = (((lane & 7) ^ lrow) & 7) * 8;

    const __bf16* aptr[4]; const __bf16* bptr[4];
#pragma unroll
    for (int i = 0; i < 4; ++i) {
        int chunk = wave * 4 + i;
        aptr[i] = A + (size_t)(m0 + chunk * 8 + lrow) * 512 + lcol;
        bptr[i] = Bm + (size_t)(n0 + chunk * 8 + lrow) * 512 + lcol;
    }

    f32x4_t acc[4][4];
#pragma unroll
    for (int i = 0; i < 4; ++i)
#pragma unroll
        for (int j = 0; j < 4; ++j) acc[i][j] = (f32x4_t){0.f, 0.f, 0.f, 0.f};

    const int l7 = lane & 7, quad = lane >> 4, c16 = lane & 15;

    for (int kk = 0; kk < 512; kk += 64) {
#pragma unroll
        for (int i = 0; i < 4; ++i) {
            int chunk = wave * 4 + i;
            async16(aptr[i] + kk, &As[chunk * 512]);
            async16(bptr[i] + kk, &Bs[chunk * 512]);
        }
        __syncthreads();
#pragma unroll
        for (int kb = 0; kb < 2; ++kb) {
            const int goff = (((kb * 4 + quad) ^ l7)) * 8;
            bf16x8_t af[4], bfv[4];
#pragma unroll
            for (int i = 0; i < 4; ++i)
                af[i] = *(const bf16x8_t*)&As[(wy * 64 + i * 16 + c16) * 64 + goff];
#pragma unroll
            for (int j = 0; j < 4; ++j)
                bfv[j] = *(const bf16x8_t*)&Bs[(wx * 64 + j * 16 + c16) * 64 + goff];
#pragma unroll
            for (int i = 0; i < 4; ++i)
#pragma unroll
                for (int j = 0; j < 4; ++j)
                    acc[i][j] = __builtin_amdgcn_mfma_f32_16x16x32_bf16(
                        af[i], bfv[j], acc[i][j], 0, 0, 0);
        }
        __syncthreads();
    }

#pragma unroll
    for (int i = 0; i < 4; ++i) {
#pragma unroll
        for (int rr = 0; rr < 4; ++rr) {
            const int row = wy * 64 + i * 16 + quad * 4 + rr;   // local row
            const size_t rowbase = (size_t)(m0 + row) * SCLD;
            float v[4]; float m = -FLT_MAX;
#pragma unroll
            for (int j = 0; j < 4; ++j) {
                int col = n0 + wx * 64 + j * 16 + c16;
                __bf16 xb = (__bf16)acc[i][j][rr];
                if (col < NCAND) {
                    scB[rowbase + col] = xb;
                    float xr = (float)xb;
                    v[j] = xr; m = fmaxf(m, xr);
                } else v[j] = -FLT_MAX;
            }
            float s = 0.f;
#pragma unroll
            for (int j = 0; j < 4; ++j)
                s += (v[j] > -FLT_MAX) ? __expf(v[j] - m) : 0.f;
#pragma unroll
            for (int mk = 1; mk < 16; mk <<= 1) {
                float om = __shfl_xor(m, mk);
                float os = __shfl_xor(s, mk);
                float mm = fmaxf(m, om);
                s = s * __expf(m - mm) + os * __expf(om - mm);
                m = mm;
            }
            if (c16 == 0) { redm[wx][row] = m; reds[wx][row] = s; }
        }
    }
    __syncthreads();
    if (tid < 128) {
        float ma = redm[0][tid], sa = reds[0][tid];
        float mb = redm[1][tid], sb = reds[1][tid];
        float mm = fmaxf(ma, mb);
        float ss = sa * __expf(ma - mm) + sb * __expf(mb - mm);
        pmax[(size_t)nt * MG + m0 + tid] = mm;
        psum[(size_t)nt * MG + m0 + tid] = ss;
    }
}

// ---------------------------------------------------------------------------
// Attention: one block per (b,h); K/V/Q head-slices staged in LDS once.
// 256 threads = 16 queries x 16 lanes. tanh fused at write.
// ---------------------------------------------------------------------------
#define KPAD 72
__global__ __launch_bounds__(256) void attn_kernel(const __bf16* __restrict__ Qg,
                                                   const __bf16* __restrict__ K,
                                                   const __bf16* __restrict__ V,
                                                   __bf16* __restrict__ attnB) {
    const int b = blockIdx.x, h = blockIdx.y, t = threadIdx.x;
    __shared__ __bf16 Ks[128 * KPAD];
    __shared__ __bf16 Vs[128 * KPAD];
    __shared__ float  Qs[16 * 68];
    __shared__ float  P[16 * 130];

    for (int i = t; i < 1024; i += 256) {
        int row = i >> 3, cg = (i & 7) * 8;
        size_t gsrc = ((size_t)(b * S_CURR + row)) * D + h * DH + cg;
        *(bf16x8_t*)&Ks[row * KPAD + cg] = *(const bf16x8_t*)&K[gsrc];
        *(bf16x8_t*)&Vs[row * KPAD + cg] = *(const bf16x8_t*)&V[gsrc];
    }
    if (t < 128) {
        int q = t >> 3, cg = (t & 7) * 8;
        bf16x8_t qv = *(const bf16x8_t*)&Qg[((size_t)(b * NM + q)) * D + h * DH + cg];
#pragma unroll
        for (int u = 0; u < 8; ++u) Qs[q * 68 + cg + u] = (float)qv[u];
    }
    __syncthreads();

    const int q = t >> 4, i = t & 15;
    float sv[8];
    float lmax = -FLT_MAX;
#pragma unroll
    for (int z = 0; z < 8; ++z) {
        int kk = i + z * 16;
        float s = 0.f;
#pragma unroll
        for (int d0 = 0; d0 < DH; d0 += 8) {
            bf16x8_t kv = *(const bf16x8_t*)&Ks[kk * KPAD + d0];
#pragma unroll
            for (int u = 0; u < 8; ++u) s += Qs[q * 68 + d0 + u] * (float)kv[u];
        }
        sv[z] = s; lmax = fmaxf(lmax, s);
    }
#pragma unroll
    for (int mk = 1; mk < 16; mk <<= 1) lmax = fmaxf(lmax, __shfl_xor(lmax, mk));
    float lsum = 0.f;
#pragma unroll
    for (int z = 0; z < 8; ++z) {
        float e = __expf(sv[z] - lmax);
        P[q * 130 + i + z * 16] = e;
        lsum += e;
    }
#pragma unroll
    for (int mk = 1; mk < 16; mk <<= 1) lsum += __shfl_xor(lsum, mk);
    const float inv = 1.0f / lsum;

    // P[q][*] produced and consumed by the same wave (q-group within wave) —
    // wave-order LDS semantics make this safe without a block barrier.
    const int d = i * 4;
    float a0 = 0.f, a1 = 0.f, a2 = 0.f, a3 = 0.f;
    for (int kk = 0; kk < 128; ++kk) {
        float p = P[q * 130 + kk];
        const __bf16* vr = &Vs[kk * KPAD + d];
        a0 += p * (float)vr[0]; a1 += p * (float)vr[1];
        a2 += p * (float)vr[2]; a3 += p * (float)vr[3];
    }
    __bf16* o = attnB + ((size_t)(b * NM + q)) * D + h * DH + d;
    o[0] = (__bf16)tanhf(a0 * inv); o[1] = (__bf16)tanhf(a1 * inv);
    o[2] = (__bf16)tanhf(a2 * inv); o[3] = (__bf16)tanhf(a3 * inv);
}

// ---------------------------------------------------------------------------
__global__ __launch_bounds__(256) void lse_reduce(const float* __restrict__ pmax,
                                                  const float* __restrict__ psum,
                                                  float* __restrict__ lse) {
    int row = blockIdx.x, t = threadIdx.x;
    float m = -FLT_MAX, s = 0.f;
    for (int i = t; i < NT; i += 256) {
        float om = pmax[(size_t)i * MG + row];
        float os = psum[(size_t)i * MG + row];
        float mm = fmaxf(m, om);
        s = s * __expf(m - mm) + os * __expf(om - mm);
        m = mm;
    }
    __shared__ float ms[256], ss[256];
    ms[t] = m; ss[t] = s;
    __syncthreads();
    for (int off = 128; off > 0; off >>= 1) {
        if (t < off) {
            float m1 = ms[t], s1 = ss[t], m2 = ms[t + off], s2 = ss[t + off];
            float mm = fmaxf(m1, m2);
            ms[t] = mm;
            ss[t] = s1 * __expf(m1 - mm) + s2 * __expf(m2 - mm);
        }
        __syncthreads();
    }
    if (t == 0) lse[row] = ms[0] + logf(ss[0]);
}

// ---------------------------------------------------------------------------
__global__ __launch_bounds__(256) void final_out(const __bf16* __restrict__ scB,
                                                 const float* __restrict__ lse,
                                                 float* __restrict__ out) {
    int row = blockIdx.y;
    int c0 = (blockIdx.x * 256 + threadIdx.x) * 8;
    if (c0 >= NCAND) return;
    float l = lse[row];
    bf16x8_t v = *(const bf16x8_t*)(scB + (size_t)row * SCLD + c0);
    float* o = out + (size_t)row * NCAND + c0;
    if (c0 + 8 <= NCAND) {
        *(float2*)(o)     = make_float2((float)v[0] - l, (float)v[1] - l);
        *(float2*)(o + 2) = make_float2((float)v[2] - l, (float)v[3] - l);
        *(float2*)(o + 4) = make_float2((float)v[4] - l, (float)v[5] - l);
        *(float2*)(o + 6) = make_float2((float)v[6] - l, (float)v[7] - l);
    } else {
        for (int k2 = 0; k2 < NCAND - c0; ++k2) o[k2] = (float)v[k2] - l;
    }
}

// ---------------------------------------------------------------------------
extern "C" void kernel_launch(void* const* d_in, const int* in_sizes, int n_in,
                              void* d_out, int out_size, void* d_ws, size_t ws_size,
                              hipStream_t stream) {
    const int*   mask_pos = (const int*)d_in[2];
    const int*   curr_idx = (const int*)d_in[3];
    const float* emb      = (const float*)d_in[5];
    const float* c_wq = (const float*)d_in[12];
    const float* c_bq = (const float*)d_in[13];
    const float* c_wk = (const float*)d_in[14];
    const float* c_bk = (const float*)d_in[15];
    const float* c_wv = (const float*)d_in[16];
    const float* c_bv = (const float*)d_in[17];
    const float* t2_w = (const float*)d_in[24];
    const float* t2_b = (const float*)d_in[25];
    float* out = (float*)d_out;

    char* w = (char*)d_ws;
    __bf16* embB  = (__bf16*)w;                           // 40064x512 bf16 = 41 MB
    __bf16* scB   = (__bf16*)(w + 41025536);              // 512x40064 bf16 = 41 MB
    __bf16* currB = scB;                                  // overlay (dead pre-scores)
    __bf16* Kf    = (__bf16*)(w + 41025536 + 4194304);
    __bf16* Vf    = (__bf16*)(w + 41025536 + 8388608);
    __bf16* Qg    = (__bf16*)(w + 41025536 + 12582912);
    __bf16* attnB = (__bf16*)(w + 41025536 + 13107200);
    __bf16* wqB   = (__bf16*)(w + 41025536 + 13631488);
    __bf16* wkB   = (__bf16*)(w + 41025536 + 14155776);
    __bf16* wvB   = (__bf16*)(w + 41025536 + 14680064);
    __bf16* t2wB  = (__bf16*)(w + 41025536 + 15204352);
    int*    qidx  = (int*)   (w + 41025536 + 15728640);
    __bf16* gatheredB = (__bf16*)(w + 82051072);
    float*  pmax  = (float*)(w + 82575360);
    float*  psum  = (float*)(w + 83216384);
    float*  lse   = (float*)(w + 83857408);

    hipLaunchKernelGGL(prep_kernel, dim3(14609), dim3(256), 0, stream,
                       emb, c_wq, c_wk, c_wv, t2_w, embB, wqB, wkB, wvB, t2wB,
                       curr_idx, currB, mask_pos, qidx);
    // K (z=0), V (z=1), Q-gathered (z=2, only 4 M-tiles) in one dispatch
    hipLaunchKernelGGL(gemm_bf, dim3(32, 4, 3), dim3(256), 0, stream,
                       currB, wkB, c_bk, Kf, wvB, c_bv, Vf, wqB, c_bq, Qg, qidx);
    hipLaunchKernelGGL(attn_kernel, dim3(B, H), dim3(256), 0, stream,
                       Qg, Kf, Vf, attnB);
    hipLaunchKernelGGL(gemm_bf, dim3(4, 4, 1), dim3(256), 0, stream,
                       attnB, t2wB, t2_b, gatheredB,
                       t2wB, t2_b, gatheredB, t2wB, t2_b, gatheredB,
                       (const int*)nullptr);
    hipLaunchKernelGGL(gemm_scores, dim3(1280), dim3(256), 0, stream,
                       gatheredB, embB, scB, pmax, psum);
    hipLaunchKernelGGL(lse_reduce, dim3(MG), dim3(256), 0, stream, pmax, psum, lse);
    hipLaunchKernelGGL(final_out, dim3(20, MG), dim3(256), 0, stream, scB, lse, out);
}